// Round 11
// baseline (137.742 us; speedup 1.0000x reference)
//
#include <hip/hip_runtime.h>
#include <hip/hip_bf16.h>

typedef __attribute__((ext_vector_type(4))) float f32x4;
typedef _Float16 f16;
typedef __attribute__((ext_vector_type(8))) f16 f16x8;
typedef __attribute__((ext_vector_type(4))) f16 f16x4;
typedef __attribute__((ext_vector_type(2))) __fp16 fp16x2;

#define LDQ 136   // O-buffer row stride (f16): 128 + 8 pad

// Pack a row-major [K x Ntot] f32 weight into fp16 MFMA fragments (K=32 use):
// dst[((nt*4+kst)*64 + lane)*8 + e] = f16(w[32*kst + 8*(lane>>4) + e][16*nt + (lane&15)])
__global__ void pack_w_kernel(const float* __restrict__ w, f16* __restrict__ dst, int Ntot) {
  int idx = blockIdx.x * 256 + threadIdx.x;
  int total = (Ntot / 16) * 4 * 64;
  if (idx >= total) return;
  int lane = idx & 63;
  int kf = (idx >> 6) & 3;
  int nt = idx >> 8;
  int k0 = 32 * kf + 8 * (lane >> 4);
  int n = 16 * nt + (lane & 15);
  f16x8 v;
#pragma unroll
  for (int e = 0; e < 8; e++) v[e] = (f16)w[(k0 + e) * Ntot + n];
  *(f16x8*)(dst + (size_t)idx * 8) = v;
}

// Pre-pack mask TRANSPOSED into per-lane MFMA C-fragment layout for S^T tiles:
// v = nt*16 + mt*4 + r ; q = 16*nt + (l&15), key = 16*mt + 4*(l>>4) + r
__global__ void pack_mask_kernel(const float* __restrict__ mask, float* __restrict__ dst) {
  int idx = blockIdx.x * 256 + threadIdx.x;  // 64*64*64
  int v = idx & 63;
  int l = (idx >> 6) & 63;
  int w = idx >> 12;
  int r = v & 3, mt = (v >> 2) & 3, nt = v >> 4;
  int q = 16 * nt + (l & 15);
  int key = 16 * mt + 4 * (l >> 4) + r;
  float val;
  if (key >= 49) val = -1e30f;
  else if (q < 49) val = mask[w * 2401 + q * 49 + key];
  else val = 0.f;
  dst[idx] = val;
}

__device__ __forceinline__ f16x8 cvt8(const float* p) {
  f32x4 lo = *(const f32x4*)(p);
  f32x4 hi = *(const f32x4*)(p + 4);
  union { f16x8 v; fp16x2 h[4]; } u;
  u.h[0] = __builtin_amdgcn_cvt_pkrtz(lo[0], lo[1]);
  u.h[1] = __builtin_amdgcn_cvt_pkrtz(lo[2], lo[3]);
  u.h[2] = __builtin_amdgcn_cvt_pkrtz(hi[0], hi[1]);
  u.h[3] = __builtin_amdgcn_cvt_pkrtz(hi[2], hi[3]);
  return u.v;
}

__device__ __forceinline__ f16x4 pack4(f32x4 v) {
  union { f16x4 o; fp16x2 h[2]; } u;
  u.h[0] = __builtin_amdgcn_cvt_pkrtz(v[0], v[1]);
  u.h[1] = __builtin_amdgcn_cvt_pkrtz(v[2], v[3]);
  return u.o;
}

// Swapped 16x16 C-tile (col=ll, row=4*lg+r) packed to f16x4 IS the K=16 MFMA
// A/B fragment (idx=lane&15, k=4*(lane>>4)+e) — no cross-lane movement needed.

// 512-thread block = 2 independent windows (waves 0-3 -> win 0, waves 4-7 -> win 1).
// Per-wave code identical to the 256-thread version; one barrier couples 8 waves.
template <bool PM>
__global__ __launch_bounds__(512, 4) void winattn_main(
    const float* __restrict__ x, const float* __restrict__ mask,
    const float* __restrict__ mask_p,
    const float* __restrict__ bqkv, const float* __restrict__ bproj,
    const f16* __restrict__ wqkv_p, const f16* __restrict__ wproj_p,
    float* __restrict__ out) {
  __shared__ f16 Os[2][64 * LDQ];  // only O crosses waves (per window)

  const int tid = threadIdx.x;
  const int win = tid >> 8;        // 0 or 1
  const int h = (tid >> 6) & 3;    // wave-within-window == head
  const int l = tid & 63;
  const int lg = l >> 4;
  const int ll = l & 15;
  const int b = blockIdx.x * 2 + win;  // window id
  f16* Osw = &Os[win][0];

  const float* xw = x + (size_t)b * 49 * 128;

  // ---------------- stage 1: QKV = x @ Wqkv + b, results stay in registers ----------------
  f16x8 af[4][4];
#pragma unroll
  for (int t = 0; t < 4; t++) {
    int row = 16 * t + ll;
#pragma unroll
    for (int kst = 0; kst < 4; kst++) {
      if (row < 49) {
        af[t][kst] = cvt8(xw + row * 128 + kst * 32 + 8 * lg);
      } else {
        f16x8 a;
#pragma unroll
        for (int e = 0; e < 8; e++) a[e] = (f16)0.f;
        af[t][kst] = a;
      }
    }
  }
  // Q tiles (swapped: C col=token=ll, row=feature 4lg+r) -> f16x4 = stage-2 B-frag chunk
  f16x4 qv[2][4];  // [feature chunk][token tile]
#pragma unroll
  for (int mi = 0; mi < 2; mi++) {
    int ntw = 2 * h + mi;
    f16x8 wf[4];
#pragma unroll
    for (int kst = 0; kst < 4; kst++)
      wf[kst] = *(const f16x8*)(wqkv_p + (size_t)(((ntw * 4 + kst) * 64) + l) * 8);
    f32x4 bq = *(const f32x4*)(bqkv + 16 * ntw + 4 * lg);
#pragma unroll
    for (int t = 0; t < 4; t++) {
      f32x4 acc = {0.f, 0.f, 0.f, 0.f};
#pragma unroll
      for (int kst = 0; kst < 4; kst++)
        acc = __builtin_amdgcn_mfma_f32_16x16x32_f16(wf[kst], af[t][kst], acc, 0, 0, 0);
#pragma unroll
      for (int r = 0; r < 4; r++) acc[r] += bq[r];
      qv[mi][t] = pack4(acc);
    }
  }
  // K tiles (swapped) -> stage-2 A-frag chunks
  f16x4 kv[2][4];
#pragma unroll
  for (int mi = 0; mi < 2; mi++) {
    int ntw = 8 + 2 * h + mi;
    f16x8 wf[4];
#pragma unroll
    for (int kst = 0; kst < 4; kst++)
      wf[kst] = *(const f16x8*)(wqkv_p + (size_t)(((ntw * 4 + kst) * 64) + l) * 8);
    f32x4 bk = *(const f32x4*)(bqkv + 16 * ntw + 4 * lg);
#pragma unroll
    for (int t = 0; t < 4; t++) {
      f32x4 acc = {0.f, 0.f, 0.f, 0.f};
#pragma unroll
      for (int kst = 0; kst < 4; kst++)
        acc = __builtin_amdgcn_mfma_f32_16x16x32_f16(wf[kst], af[t][kst], acc, 0, 0, 0);
#pragma unroll
      for (int r = 0; r < 4; r++) acc[r] += bk[r];
      kv[mi][t] = pack4(acc);
    }
  }
  // V tiles (unswapped: C col=d=ll, row=token 4lg+r) -> stage-3 A-frag chunks
  f16x4 vv[2][4];  // [d chunk][token tile]
#pragma unroll
  for (int vi = 0; vi < 2; vi++) {
    int ntw = 16 + 2 * h + vi;
    f16x8 wf[4];
#pragma unroll
    for (int kst = 0; kst < 4; kst++)
      wf[kst] = *(const f16x8*)(wqkv_p + (size_t)(((ntw * 4 + kst) * 64) + l) * 8);
    float bv = bqkv[16 * ntw + ll];
#pragma unroll
    for (int t = 0; t < 4; t++) {
      f32x4 acc = {0.f, 0.f, 0.f, 0.f};
#pragma unroll
      for (int kst = 0; kst < 4; kst++)
        acc = __builtin_amdgcn_mfma_f32_16x16x32_f16(af[t][kst], wf[kst], acc, 0, 0, 0);
#pragma unroll
      for (int r = 0; r < 4; r++) acc[r] += bv;
      vv[vi][t] = pack4(acc);
    }
  }

  // ---------------- stage 2: S^T = K Q^T (K=16 chunks, mask as C-operand), softmax ----------------
  const f32x4* mp4 = PM ? (const f32x4*)(mask_p + (((size_t)(b & 63)) * 64 + l) * 64) : nullptr;
  const float* mk = mask + (size_t)(b & 63) * 49 * 49;
  f16x4 pb[4][4];  // [key tile mt][query tile nt] -> stage-3 B-frag chunks
#pragma unroll
  for (int nt = 0; nt < 4; nt++) {
    f32x4 s[4];
#pragma unroll
    for (int mt = 0; mt < 4; mt++) {
      f32x4 c0;
      if (PM) c0 = mp4[nt * 4 + mt];
      else c0 = (f32x4){0.f, 0.f, 0.f, 0.f};
      c0 = __builtin_amdgcn_mfma_f32_16x16x16f16(kv[0][mt], qv[0][nt], c0, 0, 0, 0);
      s[mt] = __builtin_amdgcn_mfma_f32_16x16x16f16(kv[1][mt], qv[1][nt], c0, 0, 0, 0);
    }
    if (!PM) {
#pragma unroll
      for (int mt = 0; mt < 4; mt++)
#pragma unroll
        for (int r = 0; r < 4; r++) {
          int q = 16 * nt + ll;
          int key = 16 * mt + 4 * lg + r;
          float add;
          if (key >= 49) add = -1e30f;
          else if (q < 49) add = mk[q * 49 + key];
          else add = 0.f;
          s[mt][r] += add;
        }
    }
    // softmax for query q = 16*nt + ll (16 in-lane + lanes ll, ll+16, ll+32, ll+48)
    float m01 = fmaxf(fmaxf(fmaxf(s[0][0], s[0][1]), fmaxf(s[0][2], s[0][3])),
                      fmaxf(fmaxf(s[1][0], s[1][1]), fmaxf(s[1][2], s[1][3])));
    float m23 = fmaxf(fmaxf(fmaxf(s[2][0], s[2][1]), fmaxf(s[2][2], s[2][3])),
                      fmaxf(fmaxf(s[3][0], s[3][1]), fmaxf(s[3][2], s[3][3])));
    float m = fmaxf(m01, m23);
    m = fmaxf(m, __shfl_xor(m, 16));
    m = fmaxf(m, __shfl_xor(m, 32));
#pragma unroll
    for (int mt = 0; mt < 4; mt++)
#pragma unroll
      for (int r = 0; r < 4; r++) s[mt][r] = __expf(s[mt][r] - m);
    float sm0 = (s[0][0] + s[0][1]) + (s[0][2] + s[0][3]);
    float sm1 = (s[1][0] + s[1][1]) + (s[1][2] + s[1][3]);
    float sm2 = (s[2][0] + s[2][1]) + (s[2][2] + s[2][3]);
    float sm3 = (s[3][0] + s[3][1]) + (s[3][2] + s[3][3]);
    float sum = (sm0 + sm1) + (sm2 + sm3);
    sum += __shfl_xor(sum, 16);
    sum += __shfl_xor(sum, 32);
    float invn = __builtin_amdgcn_rcpf(sum);
#pragma unroll
    for (int mt = 0; mt < 4; mt++) {
      f32x4 pv;
#pragma unroll
      for (int r = 0; r < 4; r++) pv[r] = s[mt][r] * invn;
      pb[mt][nt] = pack4(pv);
    }
  }

  // ---------------- stage 3: O^T = V^T P^T (K=16 chunks over key tiles) ----------------
#pragma unroll
  for (int mi = 0; mi < 2; mi++)
#pragma unroll
    for (int nq = 0; nq < 4; nq++) {
      f32x4 o = {0.f, 0.f, 0.f, 0.f};
#pragma unroll
      for (int c = 0; c < 4; c++)
        o = __builtin_amdgcn_mfma_f32_16x16x16f16(vv[mi][c], pb[c][nq], o, 0, 0, 0);
      *(f16x4*)(&Osw[(16 * nq + ll) * LDQ + 32 * h + 16 * mi + 4 * lg]) = pack4(o);
    }

  // hoist stage-4 weight fragments (VMEM hides under barrier)
  f16x8 wf2[2][4];
  f32x4 bp2[2];
#pragma unroll
  for (int moi = 0; moi < 2; moi++) {
    int mo = 2 * h + moi;
#pragma unroll
    for (int kst = 0; kst < 4; kst++)
      wf2[moi][kst] = *(const f16x8*)(wproj_p + (size_t)(((mo * 4 + kst) * 64) + l) * 8);
    bp2[moi] = *(const f32x4*)(bproj + 16 * mo + 4 * lg);
  }
  __syncthreads();  // stage 4 reads all heads' O columns (per window)

  // ---------------- stage 4: out^T = Wproj^T O^T -> coalesced f32x4 stores ----------------
  f16x8 of[4][4];
#pragma unroll
  for (int nt = 0; nt < 4; nt++)
#pragma unroll
    for (int kst = 0; kst < 4; kst++)
      of[nt][kst] = *(const f16x8*)(&Osw[(16 * nt + ll) * LDQ + 32 * kst + 8 * lg]);
#pragma unroll
  for (int moi = 0; moi < 2; moi++) {
    int mo = 2 * h + moi;
#pragma unroll
    for (int nt = 0; nt < 4; nt++) {
      f32x4 acc = {0.f, 0.f, 0.f, 0.f};
#pragma unroll
      for (int kst = 0; kst < 4; kst++)
        acc = __builtin_amdgcn_mfma_f32_16x16x32_f16(wf2[moi][kst], of[nt][kst], acc, 0, 0, 0);
#pragma unroll
      for (int r = 0; r < 4; r++) acc[r] += bp2[moi][r];
      int tok = 16 * nt + ll;
      if (tok < 49)
        *(f32x4*)(&out[((size_t)b * 49 + tok) * 128 + 16 * mo + 4 * lg]) = acc;
    }
  }
}

extern "C" void kernel_launch(void* const* d_in, const int* in_sizes, int n_in,
                              void* d_out, int out_size, void* d_ws, size_t ws_size,
                              hipStream_t stream) {
  const float* x = (const float*)d_in[0];
  const float* mask = (const float*)d_in[1];
  const float* wqkv = (const float*)d_in[2];
  const float* bqkv = (const float*)d_in[3];
  const float* wproj = (const float*)d_in[4];
  const float* bproj = (const float*)d_in[5];
  float* out = (float*)d_out;

  f16* wqkv_p = (f16*)d_ws;                   // 96 KB
  f16* wproj_p = wqkv_p + 24 * 4 * 64 * 8;    // 32 KB
  float* mask_p = (float*)((char*)d_ws + 128 * 1024);  // 1 MB

  const size_t need = 128 * 1024 + 64 * 64 * 64 * sizeof(float);
  const bool pm = ws_size >= need;

  pack_w_kernel<<<24, 256, 0, stream>>>(wqkv, wqkv_p, 384);
  pack_w_kernel<<<8, 256, 0, stream>>>(wproj, wproj_p, 128);
  if (pm) {
    pack_mask_kernel<<<1024, 256, 0, stream>>>(mask, mask_p);
    winattn_main<true><<<2048, 512, 0, stream>>>(x, mask, mask_p, bqkv, bproj, wqkv_p, wproj_p, out);
  } else {
    winattn_main<false><<<2048, 512, 0, stream>>>(x, mask, nullptr, bqkv, bproj, wqkv_p, wproj_p, out);
  }
}